// Round 19
// baseline (106.937 us; speedup 1.0000x reference)
//
#include <hip/hip_runtime.h>
#include <hip/hip_bf16.h>

typedef float f32x4 __attribute__((ext_vector_type(4)));
typedef short s16x8 __attribute__((ext_vector_type(8)));
typedef unsigned u32x4 __attribute__((ext_vector_type(4)));
typedef unsigned short u16;

__device__ __forceinline__ u16 f2bf(float f) {
    unsigned u = __float_as_uint(f);
    u += 0x7fffu + ((u >> 16) & 1u);   // RNE
    return (u16)(u >> 16);
}
__device__ __forceinline__ float bf2f(u16 u) {
    return __uint_as_float((unsigned)u << 16);
}

// 2^x for bounded inputs; compiler-visible (no raw inline asm: R9 hazard lesson).
__device__ __forceinline__ float fast_exp2(float x) {
#if __has_builtin(__builtin_amdgcn_exp2f)
    return __builtin_amdgcn_exp2f(x);
#else
    return exp2f(x);
#endif
}

#define GLDS16(gp, lp) __builtin_amdgcn_global_load_lds( \
    (const __attribute__((address_space(1))) void*)(gp), \
    (__attribute__((address_space(3))) void*)(lp), 16, 0, 0)

// ---------------- prep: weight transpose+cast (z 0-5) and input cast (z 6-7) ----------------
// z=0 (w_qk) additionally scaled by 0.125*log2(e) (softmax scale folded into qk).
__global__ __launch_bounds__(256) void prep_kernel(
    const float* w0, const float* w1, const float* w2,
    const float* w3, const float* w4, const float* w5, u16* wt_base,
    const float* x, const float* ctx, u16* xbf) {
    int z = blockIdx.z;
    int t = threadIdx.x;
    if (z < 6) {
        __shared__ float tile[64][65];
        const float* src = z==0?w0 : z==1?w1 : z==2?w2 : z==3?w3 : z==4?w4 : w5;
        const float osc = (z == 0) ? 0.18033688011112042f : 1.0f;
        u16* dst = wt_base + (size_t)z * 262144;
        int r0 = blockIdx.y * 64, c0 = blockIdx.x * 64;
        for (int it = 0; it < 4; ++it) {
            int idx = it * 256 + t;
            int r = idx >> 4, c4 = (idx & 15) << 2;
            float4 v = *(const float4*)(src + (size_t)(r0 + r) * 512 + c0 + c4);
            tile[r][c4+0] = v.x; tile[r][c4+1] = v.y; tile[r][c4+2] = v.z; tile[r][c4+3] = v.w;
        }
        __syncthreads();
        for (int it = 0; it < 4; ++it) {
            int idx = it * 256 + t;
            int c = idx >> 4, r4 = (idx & 15) << 2;
            ushort4 o;
            o.x = f2bf(tile[r4+0][c] * osc); o.y = f2bf(tile[r4+1][c] * osc);
            o.z = f2bf(tile[r4+2][c] * osc); o.w = f2bf(tile[r4+3][c] * osc);
            *(ushort4*)(dst + (size_t)(c0 + c) * 512 + r0 + r4) = o;
        }
    } else {
        const float* src = (z == 6) ? x : ctx;
        u16* dst = xbf + (size_t)(z - 6) * 2097152;
        int bid = blockIdx.y * 8 + blockIdx.x;            // 0..63
        size_t basei = (size_t)bid * 32768 + (size_t)t * 4;
        for (int it = 0; it < 32; ++it) {
            size_t i = basei + (size_t)it * 1024;
            float4 v = *(const float4*)(src + i);
            ushort4 o = { f2bf(v.x), f2bf(v.y), f2bf(v.z), f2bf(v.w) };
            *(ushort4*)(dst + i) = o;
        }
    }
}

// ---------------- projections: bf16 [4096x512] @ W -> bf16, BN=64, glds-staged ----------------
__global__ __launch_bounds__(256, 3) void proj_kernel(
    const u16* xbf, const u16* wt, u16* proj_base) {
    __shared__ u16 Al[2][128 * 64];
    __shared__ u16 Bl[2][64 * 64];
    int z = blockIdx.z;
    const u16* A = xbf + ((z < 2) ? 0 : 2097152);
    int p = (z==1) ? 2 : (z==2) ? 1 : z;
    const u16* Wt = wt + (size_t)p * 262144;
    u16* dst = proj_base + (size_t)p * 2097152;
    int m0 = blockIdx.y * 128, n0 = blockIdx.x * 64;
    int t = threadIdx.x, w = t >> 6, l = t & 63, lg = l >> 4, lr = l & 15, m7 = lr & 7;
    int lrow = l >> 3, lsw = (l & 7) ^ (lrow & 7);
    const u16* asrc = A  + (size_t)(m0 + w*32 + lrow) * 512 + lsw * 8;
    const u16* bsrc = Wt + (size_t)(n0 + w*16 + lrow) * 512 + lsw * 8;
#define PSTAGE(BUF, K0V) do { \
    u16* la_ = &Al[BUF][(w*32) * 64]; \
    u16* lb_ = &Bl[BUF][(w*16) * 64]; \
    GLDS16(asrc + (K0V),          la_); \
    GLDS16(asrc + (K0V) + 8*512,  la_ + 8*64); \
    GLDS16(asrc + (K0V) + 16*512, la_ + 16*64); \
    GLDS16(asrc + (K0V) + 24*512, la_ + 24*64); \
    GLDS16(bsrc + (K0V),          lb_); \
    GLDS16(bsrc + (K0V) + 8*512,  lb_ + 8*64); \
  } while (0)
    int offA[2][2], offB[2][4];
#pragma unroll
    for (int ks = 0; ks < 2; ++ks) {
#pragma unroll
        for (int mi = 0; mi < 2; ++mi)
            offA[ks][mi] = (w*32 + mi*16 + lr)*64 + (((ks*4 + lg) ^ m7) * 8);
#pragma unroll
        for (int nf = 0; nf < 4; ++nf)
            offB[ks][nf] = (nf*16 + lr)*64 + (((ks*4 + lg) ^ m7) * 8);
    }
    f32x4 acc[2][4] = {};
    PSTAGE(0, 0);
    for (int k0 = 0; k0 < 512; k0 += 64) {
        int cur = (k0 >> 6) & 1;
        asm volatile("s_waitcnt vmcnt(0)" ::: "memory");
        __syncthreads();
        if (k0 < 512 - 64) PSTAGE(cur ^ 1, k0 + 64);
        const u16* al_ = &Al[cur][0];
        const u16* bl_ = &Bl[cur][0];
#pragma unroll
        for (int ks = 0; ks < 2; ++ks) {
            s16x8 a[2], b[4];
#pragma unroll
            for (int mi = 0; mi < 2; ++mi) a[mi] = *(const s16x8*)&al_[offA[ks][mi]];
#pragma unroll
            for (int nf = 0; nf < 4; ++nf) b[nf] = *(const s16x8*)&bl_[offB[ks][nf]];
#pragma unroll
            for (int mi = 0; mi < 2; ++mi)
#pragma unroll
                for (int nf = 0; nf < 4; ++nf)
                    acc[mi][nf] = __builtin_amdgcn_mfma_f32_16x16x32_bf16(a[mi], b[nf], acc[mi][nf], 0, 0, 0);
        }
    }
#undef PSTAGE
    if (z & 1) {
        for (int mi = 0; mi < 2; ++mi) {
            int row = m0 + w*32 + mi*16 + lg*4;
            int b = row >> 11, n = row & 2047;
            for (int nf = 0; nf < 4; ++nf) {
                int c = n0 + nf*16 + lr;
                int h = c >> 6, d = c & 63;
                ushort4 o = { f2bf(acc[mi][nf][0]), f2bf(acc[mi][nf][1]),
                              f2bf(acc[mi][nf][2]), f2bf(acc[mi][nf][3]) };
                *(ushort4*)(dst + (((size_t)b*8 + h)*64 + d)*2048 + n) = o;
            }
        }
    } else {
        for (int mi = 0; mi < 2; ++mi) {
            int row = m0 + w*32 + mi*16 + lg*4;
            for (int nf = 0; nf < 4; ++nf) {
                int c = n0 + nf*16 + lr;
                int h = c >> 6, d = c & 63;
                for (int r = 0; r < 4; ++r) {
                    int rr = row + r;
                    int b = rr >> 11, n = rr & 2047;
                    dst[(((size_t)b*8 + h)*2048 + n)*64 + d] = f2bf(acc[mi][nf][r]);
                }
            }
        }
    }
}

// ---------------- fused bidirectional attention, j-split x2 (R17 proven, NO setprio) ----------------
__global__ __launch_bounds__(256, 4) void attn_jsplit(
    const u16* qk, const u16* cqk, const u16* vtg, const u16* cvtg,
    u16* pacc, float* denb) {
    __shared__ u16 Bt[2][64 * 64];
    __shared__ u16 Vs[2][64 * 64];
    int id = blockIdx.x + 16 * (blockIdx.y + 16 * blockIdx.z);   // 1024 blocks
    int sv = (id & 7) * 128 + (id >> 3);                          // bijective XCD chunking
    int iblk = sv & 15, bh = (sv >> 4) & 15;
    int dj = sv >> 8;                 // dir = dj&1, jh = dj>>1
    int dir = dj & 1, jh = dj >> 1;
    int i0 = iblk * 128, jbase = jh * 1024;
    const u16* Arows = dir ? cqk : qk;
    const u16* Brows = dir ? qk  : cqk;
    const u16* VTg   = dir ? vtg : cvtg;
    int b = bh >> 3, h = bh & 7;
    int t = threadIdx.x, w = t >> 6, l = t & 63, lg = l >> 4, lr = l & 15, m7 = lr & 7;
    const size_t base  = (size_t)bh * 2048 * 64;
    const size_t vbase = (size_t)bh * 64 * 2048;
    int lrow = l >> 3, lchk = l & 7, lsw = lchk ^ lrow;
    const u16* bsrc = Brows + base + (size_t)lrow * 64 + lsw * 8;
    const u16* vsrc = VTg + vbase + (size_t)(w*16 + lrow) * 2048 + lsw * 8;
#define STAGE(BUF, J0V) do { \
    const u16* bp_ = bsrc + (size_t)((J0V) + w*16) * 64; \
    const u16* vp_ = vsrc + (J0V); \
    u16* lb_ = &Bt[BUF][(w*16) * 64]; \
    u16* lv_ = &Vs[BUF][(w*16) * 64]; \
    GLDS16(bp_,          lb_); \
    GLDS16(bp_ + 8*64,   lb_ + 8*64); \
    GLDS16(vp_,          lv_); \
    GLDS16(vp_ + 8*2048, lv_ + 8*64); \
  } while (0)
    int offK[2][4];
#pragma unroll
    for (int ks = 0; ks < 2; ++ks)
#pragma unroll
        for (int nf = 0; nf < 4; ++nf)
            offK[ks][nf] = (nf*16 + lr)*64 + (((ks*4 + lg) ^ m7) * 8);
    s16x8 aq[2][2];
#pragma unroll
    for (int qb = 0; qb < 2; ++qb)
#pragma unroll
        for (int ks = 0; ks < 2; ++ks)
            aq[qb][ks] = *(const s16x8*)(Arows + base + (size_t)(i0 + w*32 + qb*16 + lr) * 64 + ks*32 + lg*8);
    const f32x4 FZ = {0.f, 0.f, 0.f, 0.f};      // loop-invariant zero C-in
    s16x8 ONES;                                  // bf16 1.0 fragment for den-via-MFMA
#pragma unroll
    for (int i = 0; i < 8; ++i) ONES[i] = (short)0x3F80;
    f32x4 acc[2][4] = {};
    f32x4 dacc[2] = {};
    STAGE(0, jbase);
    for (int j0 = jbase; j0 < jbase + 1024; j0 += 64) {
        int cur = (j0 >> 6) & 1;
        asm volatile("s_waitcnt vmcnt(0)" ::: "memory");
        __syncthreads();
        if (j0 < jbase + 1024 - 64) STAGE(cur ^ 1, j0 + 64);
        const u16* bt_ = &Bt[cur][0];
        const u16* vs_ = &Vs[cur][0];
        // QK^T: zero-init-free (C-in = FZ for ks=0)
        f32x4 s[2][4];
#pragma unroll
        for (int nf = 0; nf < 4; ++nf) {
            const s16x8 af0 = *(const s16x8*)&bt_[offK[0][nf]];
            const s16x8 af1 = *(const s16x8*)&bt_[offK[1][nf]];
#pragma unroll
            for (int qb = 0; qb < 2; ++qb) {
                f32x4 tq = __builtin_amdgcn_mfma_f32_16x16x32_bf16(af0, aq[qb][0], FZ, 0, 0, 0);
                s[qb][nf] = __builtin_amdgcn_mfma_f32_16x16x32_bf16(af1, aq[qb][1], tq, 0, 0, 0);
            }
        }
        // V-frags: read once, shared by both qb
        s16x8 bvv[2][4];
#pragma unroll
        for (int ks2 = 0; ks2 < 2; ++ks2)
#pragma unroll
            for (int nf = 0; nf < 4; ++nf)
                bvv[ks2][nf] = *(const s16x8*)&vs_[offK[ks2][nf]];
#pragma unroll
        for (int qb = 0; qb < 2; ++qb) {
            unsigned PK0[4], PK1[4];
#pragma unroll
            for (int nf = 0; nf < 4; ++nf) {
                float e0 = fast_exp2(s[qb][nf][0]), e1 = fast_exp2(s[qb][nf][1]);
                float e2 = fast_exp2(s[qb][nf][2]), e3 = fast_exp2(s[qb][nf][3]);
                asm("v_cvt_pk_bf16_f32 %0, %1, %2" : "=v"(PK0[nf]) : "v"(e0), "v"(e1));
                asm("v_cvt_pk_bf16_f32 %0, %1, %2" : "=v"(PK1[nf]) : "v"(e2), "v"(e3));
            }
#pragma unroll
            for (int ks2 = 0; ks2 < 2; ++ks2) {
                unsigned a0 = PK0[2*ks2], b0 = PK0[2*ks2+1];
                unsigned a1 = PK1[2*ks2], b1 = PK1[2*ks2+1];
                asm("v_permlane32_swap_b32 %0, %1" : "+v"(a0), "+v"(b0));
                asm("v_permlane16_swap_b32 %0, %1" : "+v"(a0), "+v"(b0));
                asm("v_permlane32_swap_b32 %0, %1" : "+v"(a1), "+v"(b1));
                asm("v_permlane16_swap_b32 %0, %1" : "+v"(a1), "+v"(b1));
                u32x4 fw = { a0, a1, b0, b1 };
                s16x8 ap = __builtin_bit_cast(s16x8, fw);
#pragma unroll
                for (int nf = 0; nf < 4; ++nf)
                    acc[qb][nf] = __builtin_amdgcn_mfma_f32_16x16x32_bf16(ap, bvv[ks2][nf], acc[qb][nf], 0, 0, 0);
                dacc[qb] = __builtin_amdgcn_mfma_f32_16x16x32_bf16(ap, ONES, dacc[qb], 0, 0, 0);
            }
        }
    }
#undef STAGE
    // dacc[qb][q] = partial den for row i0+w*32+qb*16+lg*4+q (identical across lr)
    if (lr == 0) {
        int dbase = ((dj * 16 + bh) << 11);
#pragma unroll
        for (int qb = 0; qb < 2; ++qb)
#pragma unroll
            for (int q = 0; q < 4; ++q)
                denb[dbase + i0 + w*32 + qb*16 + lg*4 + q] = dacc[qb][q];
    }
    u16* pdst = pacc + (size_t)dj * 2097152;
#pragma unroll
    for (int qb = 0; qb < 2; ++qb)
#pragma unroll
        for (int nf = 0; nf < 4; ++nf)
#pragma unroll
            for (int q = 0; q < 4; ++q) {
                int row = i0 + w*32 + qb*16 + lg*4 + q;
                int c = h*64 + nf*16 + lr;
                pdst[((size_t)b*2048 + row)*512 + c] = f2bf(acc[qb][nf][q]);
            }
}

// ---------------- fallback: single-pass attention (R13 proven, used if ws too small) ----------------
__global__ __launch_bounds__(256, 4) void attn_single(
    const u16* qk, const u16* cqk, const u16* vtg, const u16* cvtg,
    u16* outh, u16* ctxh) {
    __shared__ u16 Bt[2][64 * 64];
    __shared__ u16 Vs[2][64 * 64];
    int id = blockIdx.x + 16 * (blockIdx.y + 16 * blockIdx.z);
    int sv = ((id & 7) << 6) | (id >> 3);
    int dir = sv >> 8;
    int bh  = (sv >> 4) & 15;
    int i0  = (sv & 15) * 128;
    const u16* Arows = dir ? cqk : qk;
    const u16* Brows = dir ? qk  : cqk;
    const u16* VTg   = dir ? vtg : cvtg;
    u16* Out         = dir ? ctxh : outh;
    int b = bh >> 3, h = bh & 7;
    int t = threadIdx.x, w = t >> 6, l = t & 63, lg = l >> 4, lr = l & 15, m7 = lr & 7;
    const size_t base  = (size_t)bh * 2048 * 64;
    const size_t vbase = (size_t)bh * 64 * 2048;
    int lrow = l >> 3, lchk = l & 7, lsw = lchk ^ lrow;
    const u16* bsrc = Brows + base + (size_t)lrow * 64 + lsw * 8;
    const u16* vsrc = VTg + vbase + (size_t)(w*16 + lrow) * 2048 + lsw * 8;
#define STAGE(BUF, J0V) do { \
    const u16* bp_ = bsrc + (size_t)((J0V) + w*16) * 64; \
    const u16* vp_ = vsrc + (J0V); \
    u16* lb_ = &Bt[BUF][(w*16) * 64]; \
    u16* lv_ = &Vs[BUF][(w*16) * 64]; \
    GLDS16(bp_,          lb_); \
    GLDS16(bp_ + 8*64,   lb_ + 8*64); \
    GLDS16(vp_,          lv_); \
    GLDS16(vp_ + 8*2048, lv_ + 8*64); \
  } while (0)
    int offK[2][4];
#pragma unroll
    for (int ks = 0; ks < 2; ++ks)
#pragma unroll
        for (int nf = 0; nf < 4; ++nf)
            offK[ks][nf] = (nf*16 + lr)*64 + (((ks*4 + lg) ^ m7) * 8);
    s16x8 aq[2][2];
#pragma unroll
    for (int qb = 0; qb < 2; ++qb)
#pragma unroll
        for (int ks = 0; ks < 2; ++ks)
            aq[qb][ks] = *(const s16x8*)(Arows + base + (size_t)(i0 + w*32 + qb*16 + lr) * 64 + ks*32 + lg*8);
    f32x4 acc[2][4] = {};
    float den[2] = {0.f, 0.f};
    STAGE(0, 0);
    for (int j0 = 0; j0 < 2048; j0 += 64) {
        int cur = (j0 >> 6) & 1;
        asm volatile("s_waitcnt vmcnt(0)" ::: "memory");
        __syncthreads();
        if (j0 < 2048 - 64) STAGE(cur ^ 1, j0 + 64);
        const u16* bt_ = &Bt[cur][0];
        const u16* vs_ = &Vs[cur][0];
        f32x4 s[2][4];
#pragma unroll
        for (int nf = 0; nf < 4; ++nf) {
            s[0][nf] = (f32x4){0.f,0.f,0.f,0.f};
            s[1][nf] = (f32x4){0.f,0.f,0.f,0.f};
#pragma unroll
            for (int ks = 0; ks < 2; ++ks) {
                const s16x8 af = *(const s16x8*)&bt_[offK[ks][nf]];
                s[0][nf] = __builtin_amdgcn_mfma_f32_16x16x32_bf16(af, aq[0][ks], s[0][nf], 0, 0, 0);
                s[1][nf] = __builtin_amdgcn_mfma_f32_16x16x32_bf16(af, aq[1][ks], s[1][nf], 0, 0, 0);
            }
        }
#pragma unroll
        for (int qb = 0; qb < 2; ++qb) {
            unsigned PK0[4], PK1[4];
#pragma unroll
            for (int nf = 0; nf < 4; ++nf) {
                float e0 = fast_exp2(s[qb][nf][0]), e1 = fast_exp2(s[qb][nf][1]);
                float e2 = fast_exp2(s[qb][nf][2]), e3 = fast_exp2(s[qb][nf][3]);
                den[qb] += (e0 + e1) + (e2 + e3);
                asm("v_cvt_pk_bf16_f32 %0, %1, %2" : "=v"(PK0[nf]) : "v"(e0), "v"(e1));
                asm("v_cvt_pk_bf16_f32 %0, %1, %2" : "=v"(PK1[nf]) : "v"(e2), "v"(e3));
            }
#pragma unroll
            for (int ks2 = 0; ks2 < 2; ++ks2) {
                unsigned a0 = PK0[2*ks2], b0 = PK0[2*ks2+1];
                unsigned a1 = PK1[2*ks2], b1 = PK1[2*ks2+1];
                asm("v_permlane32_swap_b32 %0, %1" : "+v"(a0), "+v"(b0));
                asm("v_permlane16_swap_b32 %0, %1" : "+v"(a0), "+v"(b0));
                asm("v_permlane32_swap_b32 %0, %1" : "+v"(a1), "+v"(b1));
                asm("v_permlane16_swap_b32 %0, %1" : "+v"(a1), "+v"(b1));
                u32x4 fw = { a0, a1, b0, b1 };
                s16x8 ap = __builtin_bit_cast(s16x8, fw);
#pragma unroll
                for (int nf = 0; nf < 4; ++nf) {
                    const s16x8 bv = *(const s16x8*)&vs_[offK[ks2][nf]];
                    acc[qb][nf] = __builtin_amdgcn_mfma_f32_16x16x32_bf16(ap, bv, acc[qb][nf], 0, 0, 0);
                }
            }
        }
    }
#undef STAGE
#pragma unroll
    for (int qb = 0; qb < 2; ++qb) {
        den[qb] += __shfl_xor(den[qb], 16);
        den[qb] += __shfl_xor(den[qb], 32);
    }
#pragma unroll
    for (int qb = 0; qb < 2; ++qb) {
        float rq[4];
#pragma unroll
        for (int q = 0; q < 4; ++q) rq[q] = 1.0f / __shfl(den[qb], lg*4 + q);
#pragma unroll
        for (int nf = 0; nf < 4; ++nf)
#pragma unroll
            for (int q = 0; q < 4; ++q) {
                int row = i0 + w*32 + qb*16 + lg*4 + q;
                int c = h*64 + nf*16 + lr;
                Out[((size_t)b*2048 + row)*512 + c] = f2bf(acc[qb][nf][q] * rq[q]);
            }
    }
}

// ---------------- fused out_gemm: normalize (a0+a1)*rden on A-staging, @ W + bias -> f32 ----------------
__global__ __launch_bounds__(256, 2) void out_gemm_fused(
    const u16* pacc, const float* denb, const u16* wt,
    const float* bias0, const float* bias1, float* out) {
    __shared__ u16 Al[64][72];
    __shared__ u16 Bl[128][72];
    __shared__ float rden[64][8];
    int z = blockIdx.z;
    const u16* A0 = pacc + (size_t)z * 2097152;
    const u16* A1 = pacc + (size_t)(2 + z) * 2097152;
    const u16* Wt = wt + (size_t)(4 + z) * 262144;
    const float* bias = z ? bias1 : bias0;
    float* dst = out + (size_t)z * 2097152;
    int m0 = blockIdx.y * 64, n0 = blockIdx.x * 128;
    int t = threadIdx.x, w = t >> 6, l = t & 63, lg = l >> 4, lr = l & 15;
    // load per-(row,head) reciprocal denominators (512 entries, 2 per thread)
    for (int it = 0; it < 2; ++it) {
        int idx = it * 256 + t;
        int r = idx >> 3, hh = idx & 7;
        int rowg = m0 + r;
        int b = rowg >> 11, row = rowg & 2047;
        int bh = b * 8 + hh;
        float d0 = denb[((z     * 16 + bh) << 11) + row];
        float d1 = denb[(((2+z) * 16 + bh) << 11) + row];
        rden[r][hh] = 1.0f / (d0 + d1);
    }
    f32x4 acc[8] = {};
    for (int k0 = 0; k0 < 512; k0 += 64) {
        __syncthreads();
        int hh = k0 >> 6;                          // head of this k-slab
        for (int it = 0; it < 2; ++it) {           // A: 64x64, normalized on the fly
            int idx = it * 256 + t;
            int r = idx >> 3, c8 = (idx & 7) << 3;
            size_t off = (size_t)(m0 + r) * 512 + k0 + c8;
            ushort4 v0 = *(const ushort4*)(A0 + off);
            ushort4 v1 = *(const ushort4*)(A0 + off + 4);
            ushort4 u0 = *(const ushort4*)(A1 + off);
            ushort4 u1 = *(const ushort4*)(A1 + off + 4);
            float rq = rden[r][hh];
            ushort4 o0, o1;
            o0.x = f2bf((bf2f(v0.x) + bf2f(u0.x)) * rq);
            o0.y = f2bf((bf2f(v0.y) + bf2f(u0.y)) * rq);
            o0.z = f2bf((bf2f(v0.z) + bf2f(u0.z)) * rq);
            o0.w = f2bf((bf2f(v0.w) + bf2f(u0.w)) * rq);
            o1.x = f2bf((bf2f(v1.x) + bf2f(u1.x)) * rq);
            o1.y = f2bf((bf2f(v1.y) + bf2f(u1.y)) * rq);
            o1.z = f2bf((bf2f(v1.z) + bf2f(u1.z)) * rq);
            o1.w = f2bf((bf2f(v1.w) + bf2f(u1.w)) * rq);
            *(ushort4*)&Al[r][c8] = o0;
            *(ushort4*)&Al[r][c8 + 4] = o1;
        }
        for (int it = 0; it < 4; ++it) {           // B: 128x64
            int idx = it * 256 + t;
            int r = idx >> 3, c8 = (idx & 7) << 3;
            *(s16x8*)&Bl[r][c8] = *(const s16x8*)(Wt + (size_t)(n0 + r) * 512 + k0 + c8);
        }
        __syncthreads();
        for (int ks = 0; ks < 2; ++ks) {
            s16x8 a = *(const s16x8*)&Al[w*16 + lr][ks*32 + lg*8];
            for (int nf = 0; nf < 8; ++nf) {
                s16x8 b = *(const s16x8*)&Bl[nf*16 + lr][ks*32 + lg*8];
                acc[nf] = __builtin_amdgcn_mfma_f32_16x16x32_bf16(a, b, acc[nf], 0, 0, 0);
            }
        }
    }
    int row = m0 + w*16 + lg*4;
    for (int nf = 0; nf < 8; ++nf) {
        int c = n0 + nf*16 + lr;
        float bv = bias[c];
        for (int r = 0; r < 4; ++r)
            dst[(size_t)(row + r) * 512 + c] = acc[nf][r] + bv;
    }
}

// ---------------- plain out_gemm (fallback path, reads outh/ctxh) ----------------
__global__ __launch_bounds__(256, 2) void out_gemm(
    const u16* heads_base, const u16* wt, const float* bias0, const float* bias1, float* out) {
    __shared__ u16 Al[64][72];
    __shared__ u16 Bl[128][72];
    int z = blockIdx.z;
    const u16* A = heads_base + (size_t)z * 2097152;
    const u16* Wt = wt + (size_t)(4 + z) * 262144;
    const float* bias = z ? bias1 : bias0;
    float* dst = out + (size_t)z * 2097152;
    int m0 = blockIdx.y * 64, n0 = blockIdx.x * 128;
    int t = threadIdx.x, w = t >> 6, l = t & 63, lg = l >> 4, lr = l & 15;
    f32x4 acc[8] = {};
    for (int k0 = 0; k0 < 512; k0 += 64) {
        __syncthreads();
        for (int it = 0; it < 2; ++it) {
            int idx = it * 256 + t;
            int r = idx >> 3, c8 = (idx & 7) << 3;
            *(s16x8*)&Al[r][c8] = *(const s16x8*)(A + (size_t)(m0 + r) * 512 + k0 + c8);
        }
        for (int it = 0; it < 4; ++it) {
            int idx = it * 256 + t;
            int r = idx >> 3, c8 = (idx & 7) << 3;
            *(s16x8*)&Bl[r][c8] = *(const s16x8*)(Wt + (size_t)(n0 + r) * 512 + k0 + c8);
        }
        __syncthreads();
        for (int ks = 0; ks < 2; ++ks) {
            s16x8 a = *(const s16x8*)&Al[w*16 + lr][ks*32 + lg*8];
            for (int nf = 0; nf < 8; ++nf) {
                s16x8 b = *(const s16x8*)&Bl[nf*16 + lr][ks*32 + lg*8];
                acc[nf] = __builtin_amdgcn_mfma_f32_16x16x32_bf16(a, b, acc[nf], 0, 0, 0);
            }
        }
    }
    int row = m0 + w*16 + lg*4;
    for (int nf = 0; nf < 8; ++nf) {
        int c = n0 + nf*16 + lr;
        float bv = bias[c];
        for (int r = 0; r < 4; ++r)
            dst[(size_t)(row + r) * 512 + c] = acc[nf][r] + bv;
    }
}

extern "C" void kernel_launch(void* const* d_in, const int* in_sizes, int n_in,
                              void* d_out, int out_size, void* d_ws, size_t ws_size,
                              hipStream_t stream) {
    const float* x      = (const float*)d_in[0];
    const float* ctx    = (const float*)d_in[1];
    const float* w_qk   = (const float*)d_in[2];
    const float* w_cqk  = (const float*)d_in[3];
    const float* w_v    = (const float*)d_in[4];
    const float* w_cv   = (const float*)d_in[5];
    const float* w_out  = (const float*)d_in[6];
    const float* b_out  = (const float*)d_in[7];
    const float* w_cout = (const float*)d_in[8];
    const float* b_cout = (const float*)d_in[9];

    u16* ws   = (u16*)d_ws;
    u16* wt   = ws;                       // 6 * 262144 bf16 weights^T (w_qk^T pre-scaled)
    u16* proj = ws + 1572864;
    u16* qk   = proj;
    u16* cqk  = proj + 2097152;
    u16* vt   = proj + 2 * 2097152;
    u16* cvt  = proj + 3 * 2097152;
    u16* outh = proj + 4 * 2097152;       // fallback-path buffers; alias xbf
    u16* ctxh = proj + 5 * 2097152;
    u16* xbf  = outh;                     // cast buffer (dead before attn writes outh in fallback)
    float* denb = (float*)(ws + 14155776);            // 131072 f32 partial denominators
    u16* pacc = ws + 14155776 + 262144;               // 4 * 2097152 u16 partial accs (in ws!)
    float* out = (float*)d_out;

    const size_t WS_NEED_JSPLIT =
        (14155776ull + 262144ull + 4ull * 2097152ull) * 2;   // ~45.6 MB

    hipLaunchKernelGGL(prep_kernel, dim3(8, 8, 8), dim3(256), 0, stream,
                       w_qk, w_cqk, w_v, w_cv, w_out, w_cout, wt, x, ctx, xbf);
    hipLaunchKernelGGL(proj_kernel, dim3(8, 32, 4), dim3(256), 0, stream, xbf, wt, proj);
    if (ws_size >= WS_NEED_JSPLIT) {
        hipLaunchKernelGGL(attn_jsplit, dim3(16, 16, 4), dim3(256), 0, stream,
                           qk, cqk, vt, cvt, pacc, denb);
        hipLaunchKernelGGL(out_gemm_fused, dim3(4, 64, 2), dim3(256), 0, stream,
                           pacc, denb, wt, b_out, b_cout, out);
    } else {
        hipLaunchKernelGGL(attn_single, dim3(16, 16, 2), dim3(256), 0, stream,
                           qk, cqk, vt, cvt, outh, ctxh);
        hipLaunchKernelGGL(out_gemm, dim3(4, 64, 2), dim3(256), 0, stream,
                           outh, wt, b_out, b_cout, out);
    }
}

// Round 21
// 93.635 us; speedup vs baseline: 1.1421x; 1.1421x over previous
//
#include <hip/hip_runtime.h>
#include <hip/hip_bf16.h>

typedef float f32x4 __attribute__((ext_vector_type(4)));
typedef short s16x8 __attribute__((ext_vector_type(8)));
typedef unsigned u32x4 __attribute__((ext_vector_type(4)));
typedef unsigned short u16;

__device__ __forceinline__ u16 f2bf(float f) {
    unsigned u = __float_as_uint(f);
    u += 0x7fffu + ((u >> 16) & 1u);   // RNE
    return (u16)(u >> 16);
}

// 2^x for bounded inputs; compiler-visible (no raw inline asm: R9 hazard lesson).
__device__ __forceinline__ float fast_exp2(float x) {
#if __has_builtin(__builtin_amdgcn_exp2f)
    return __builtin_amdgcn_exp2f(x);
#else
    return exp2f(x);
#endif
}

#define GLDS16(gp, lp) __builtin_amdgcn_global_load_lds( \
    (const __attribute__((address_space(1))) void*)(gp), \
    (__attribute__((address_space(3))) void*)(lp), 16, 0, 0)

// ---------------- input cast: x,ctx f32 -> bf16 (once) ----------------
__global__ __launch_bounds__(256) void cast_bf16(const float* x, const float* ctx, u16* xbf) {
    size_t i = ((size_t)blockIdx.x * 256 + threadIdx.x) * 4;   // 4,194,304 elems total
    const float* src = (i < 2097152) ? x : ctx;
    size_t off = (i < 2097152) ? i : i - 2097152;
    float4 v = *(const float4*)(src + off);
    ushort4 o = { f2bf(v.x), f2bf(v.y), f2bf(v.z), f2bf(v.w) };
    *(ushort4*)(xbf + i) = o;
}

// ---------------- weight transpose + bf16 cast: wt[c][k] = w[k][c] ----------------
// z=0 (w_qk) additionally scaled by 0.125*log2(e) (softmax scale folded into qk).
__global__ __launch_bounds__(256) void transpose_w(
    const float* w0, const float* w1, const float* w2,
    const float* w3, const float* w4, const float* w5, u16* wt_base) {
    __shared__ float tile[64][65];
    int z = blockIdx.z;
    const float* src = z==0?w0 : z==1?w1 : z==2?w2 : z==3?w3 : z==4?w4 : w5;
    const float osc = (z == 0) ? 0.18033688011112042f : 1.0f;
    u16* dst = wt_base + (size_t)z * 262144;
    int r0 = blockIdx.y * 64, c0 = blockIdx.x * 64;
    int t = threadIdx.x;
    for (int it = 0; it < 4; ++it) {
        int idx = it * 256 + t;
        int r = idx >> 4, c4 = (idx & 15) << 2;
        float4 v = *(const float4*)(src + (size_t)(r0 + r) * 512 + c0 + c4);
        tile[r][c4+0] = v.x; tile[r][c4+1] = v.y; tile[r][c4+2] = v.z; tile[r][c4+3] = v.w;
    }
    __syncthreads();
    for (int it = 0; it < 4; ++it) {
        int idx = it * 256 + t;
        int c = idx >> 4, r4 = (idx & 15) << 2;
        ushort4 o;
        o.x = f2bf(tile[r4+0][c] * osc); o.y = f2bf(tile[r4+1][c] * osc);
        o.z = f2bf(tile[r4+2][c] * osc); o.w = f2bf(tile[r4+3][c] * osc);
        *(ushort4*)(dst + (size_t)(c0 + c) * 512 + r0 + r4) = o;
    }
}

// ---------------- projections: bf16 [4096x512] @ W -> bf16, BN=64, glds-staged ----------------
// z=0: x*w_qk -> qk [b,h,n,64] (w pre-scaled); z=1: x*w_v -> vt [b,h,64,2048] TR
// z=2: ctx*w_cqk -> cqk;        z=3: ctx*w_cv -> cvt TR
__global__ __launch_bounds__(256, 2) void proj_kernel(
    const u16* xbf, const u16* wt, u16* proj_base) {
    __shared__ u16 Al[2][128 * 64];   // A tile, XOR-swizzled cols
    __shared__ u16 Bl[2][64 * 64];    // W^T tile, XOR-swizzled cols
    int z = blockIdx.z;
    const u16* A = xbf + ((z < 2) ? 0 : 2097152);
    int p = (z==1) ? 2 : (z==2) ? 1 : z;
    const u16* Wt = wt + (size_t)p * 262144;
    u16* dst = proj_base + (size_t)p * 2097152;
    int m0 = blockIdx.y * 128, n0 = blockIdx.x * 64;
    int t = threadIdx.x, w = t >> 6, l = t & 63, lg = l >> 4, lr = l & 15, m7 = lr & 7;
    int lrow = l >> 3, lsw = (l & 7) ^ (lrow & 7);
    const u16* asrc = A  + (size_t)(m0 + w*32 + lrow) * 512 + lsw * 8;
    const u16* bsrc = Wt + (size_t)(n0 + w*16 + lrow) * 512 + lsw * 8;
#define PSTAGE(BUF, K0V) do { \
    u16* la_ = &Al[BUF][(w*32) * 64]; \
    u16* lb_ = &Bl[BUF][(w*16) * 64]; \
    GLDS16(asrc + (K0V),          la_); \
    GLDS16(asrc + (K0V) + 8*512,  la_ + 8*64); \
    GLDS16(asrc + (K0V) + 16*512, la_ + 16*64); \
    GLDS16(asrc + (K0V) + 24*512, la_ + 24*64); \
    GLDS16(bsrc + (K0V),          lb_); \
    GLDS16(bsrc + (K0V) + 8*512,  lb_ + 8*64); \
  } while (0)
    int offA[2][2], offB[2][4];
#pragma unroll
    for (int ks = 0; ks < 2; ++ks) {
#pragma unroll
        for (int mi = 0; mi < 2; ++mi)
            offA[ks][mi] = (w*32 + mi*16 + lr)*64 + (((ks*4 + lg) ^ m7) * 8);
#pragma unroll
        for (int nf = 0; nf < 4; ++nf)
            offB[ks][nf] = (nf*16 + lr)*64 + (((ks*4 + lg) ^ m7) * 8);
    }
    f32x4 acc[2][4] = {};
    PSTAGE(0, 0);
    for (int k0 = 0; k0 < 512; k0 += 64) {
        int cur = (k0 >> 6) & 1;
        asm volatile("s_waitcnt vmcnt(0)" ::: "memory");
        __syncthreads();
        if (k0 < 512 - 64) PSTAGE(cur ^ 1, k0 + 64);
        const u16* al_ = &Al[cur][0];
        const u16* bl_ = &Bl[cur][0];
#pragma unroll
        for (int ks = 0; ks < 2; ++ks) {
            s16x8 a[2], b[4];
#pragma unroll
            for (int mi = 0; mi < 2; ++mi) a[mi] = *(const s16x8*)&al_[offA[ks][mi]];
#pragma unroll
            for (int nf = 0; nf < 4; ++nf) b[nf] = *(const s16x8*)&bl_[offB[ks][nf]];
#pragma unroll
            for (int mi = 0; mi < 2; ++mi)
#pragma unroll
                for (int nf = 0; nf < 4; ++nf)
                    acc[mi][nf] = __builtin_amdgcn_mfma_f32_16x16x32_bf16(a[mi], b[nf], acc[mi][nf], 0, 0, 0);
        }
    }
#undef PSTAGE
    if (z & 1) {
        for (int mi = 0; mi < 2; ++mi) {
            int row = m0 + w*32 + mi*16 + lg*4;
            int b = row >> 11, n = row & 2047;
            for (int nf = 0; nf < 4; ++nf) {
                int c = n0 + nf*16 + lr;
                int h = c >> 6, d = c & 63;
                ushort4 o = { f2bf(acc[mi][nf][0]), f2bf(acc[mi][nf][1]),
                              f2bf(acc[mi][nf][2]), f2bf(acc[mi][nf][3]) };
                *(ushort4*)(dst + (((size_t)b*8 + h)*64 + d)*2048 + n) = o;
            }
        }
    } else {
        for (int mi = 0; mi < 2; ++mi) {
            int row = m0 + w*32 + mi*16 + lg*4;
            for (int nf = 0; nf < 4; ++nf) {
                int c = n0 + nf*16 + lr;
                int h = c >> 6, d = c & 63;
                for (int r = 0; r < 4; ++r) {
                    int rr = row + r;
                    int b = rr >> 11, n = rr & 2047;
                    dst[(((size_t)b*8 + h)*2048 + n)*64 + d] = f2bf(acc[mi][nf][r]);
                }
            }
        }
    }
}

// ---------------- fused bidirectional attention (R13 proven body, verbatim) ----------------
// Swapped-QK in-register softmax; P fully in registers via permlane swaps.
// Sync skeleton: 2-buffer glds ring, vmcnt(0)+__syncthreads per tile.
__global__ __launch_bounds__(256, 4) void attn_single(
    const u16* qk, const u16* cqk, const u16* vtg, const u16* cvtg,
    u16* outh, u16* ctxh) {
    __shared__ u16 Bt[2][64 * 64];
    __shared__ u16 Vs[2][64 * 64];
    int id = blockIdx.x + 16 * (blockIdx.y + 16 * blockIdx.z);
    int sv = ((id & 7) << 6) | (id >> 3);
    int dir = sv >> 8;
    int bh  = (sv >> 4) & 15;
    int i0  = (sv & 15) * 128;
    const u16* Arows = dir ? cqk : qk;
    const u16* Brows = dir ? qk  : cqk;
    const u16* VTg   = dir ? vtg : cvtg;
    u16* Out         = dir ? ctxh : outh;
    int b = bh >> 3, h = bh & 7;
    int t = threadIdx.x, w = t >> 6, l = t & 63, lg = l >> 4, lr = l & 15, m7 = lr & 7;
    const size_t base  = (size_t)bh * 2048 * 64;
    const size_t vbase = (size_t)bh * 64 * 2048;
    int lrow = l >> 3, lchk = l & 7, lsw = lchk ^ lrow;
    const u16* bsrc = Brows + base + (size_t)lrow * 64 + lsw * 8;
    const u16* vsrc = VTg + vbase + (size_t)(w*16 + lrow) * 2048 + lsw * 8;
#define STAGE(BUF, J0V) do { \
    const u16* bp_ = bsrc + (size_t)((J0V) + w*16) * 64; \
    const u16* vp_ = vsrc + (J0V); \
    u16* lb_ = &Bt[BUF][(w*16) * 64]; \
    u16* lv_ = &Vs[BUF][(w*16) * 64]; \
    GLDS16(bp_,          lb_); \
    GLDS16(bp_ + 8*64,   lb_ + 8*64); \
    GLDS16(vp_,          lv_); \
    GLDS16(vp_ + 8*2048, lv_ + 8*64); \
  } while (0)
    int offK[2][4];
#pragma unroll
    for (int ks = 0; ks < 2; ++ks)
#pragma unroll
        for (int nf = 0; nf < 4; ++nf)
            offK[ks][nf] = (nf*16 + lr)*64 + (((ks*4 + lg) ^ m7) * 8);
    s16x8 aq[2][2];
#pragma unroll
    for (int qb = 0; qb < 2; ++qb)
#pragma unroll
        for (int ks = 0; ks < 2; ++ks)
            aq[qb][ks] = *(const s16x8*)(Arows + base + (size_t)(i0 + w*32 + qb*16 + lr) * 64 + ks*32 + lg*8);
    f32x4 acc[2][4] = {};
    float den[2] = {0.f, 0.f};
    STAGE(0, 0);
    for (int j0 = 0; j0 < 2048; j0 += 64) {
        int cur = (j0 >> 6) & 1;
        asm volatile("s_waitcnt vmcnt(0)" ::: "memory");
        __syncthreads();
        if (j0 < 2048 - 64) STAGE(cur ^ 1, j0 + 64);
        const u16* bt_ = &Bt[cur][0];
        const u16* vs_ = &Vs[cur][0];
        f32x4 s[2][4];
#pragma unroll
        for (int nf = 0; nf < 4; ++nf) {
            s[0][nf] = (f32x4){0.f,0.f,0.f,0.f};
            s[1][nf] = (f32x4){0.f,0.f,0.f,0.f};
#pragma unroll
            for (int ks = 0; ks < 2; ++ks) {
                const s16x8 af = *(const s16x8*)&bt_[offK[ks][nf]];
                s[0][nf] = __builtin_amdgcn_mfma_f32_16x16x32_bf16(af, aq[0][ks], s[0][nf], 0, 0, 0);
                s[1][nf] = __builtin_amdgcn_mfma_f32_16x16x32_bf16(af, aq[1][ks], s[1][nf], 0, 0, 0);
            }
        }
#pragma unroll
        for (int qb = 0; qb < 2; ++qb) {
            unsigned PK0[4], PK1[4];
#pragma unroll
            for (int nf = 0; nf < 4; ++nf) {
                float e0 = fast_exp2(s[qb][nf][0]), e1 = fast_exp2(s[qb][nf][1]);
                float e2 = fast_exp2(s[qb][nf][2]), e3 = fast_exp2(s[qb][nf][3]);
                den[qb] += (e0 + e1) + (e2 + e3);
                asm("v_cvt_pk_bf16_f32 %0, %1, %2" : "=v"(PK0[nf]) : "v"(e0), "v"(e1));
                asm("v_cvt_pk_bf16_f32 %0, %1, %2" : "=v"(PK1[nf]) : "v"(e2), "v"(e3));
            }
#pragma unroll
            for (int ks2 = 0; ks2 < 2; ++ks2) {
                unsigned a0 = PK0[2*ks2], b0 = PK0[2*ks2+1];
                unsigned a1 = PK1[2*ks2], b1 = PK1[2*ks2+1];
                asm("v_permlane32_swap_b32 %0, %1" : "+v"(a0), "+v"(b0));
                asm("v_permlane16_swap_b32 %0, %1" : "+v"(a0), "+v"(b0));
                asm("v_permlane32_swap_b32 %0, %1" : "+v"(a1), "+v"(b1));
                asm("v_permlane16_swap_b32 %0, %1" : "+v"(a1), "+v"(b1));
                u32x4 fw = { a0, a1, b0, b1 };
                s16x8 ap = __builtin_bit_cast(s16x8, fw);
#pragma unroll
                for (int nf = 0; nf < 4; ++nf) {
                    const s16x8 bv = *(const s16x8*)&vs_[offK[ks2][nf]];
                    acc[qb][nf] = __builtin_amdgcn_mfma_f32_16x16x32_bf16(ap, bv, acc[qb][nf], 0, 0, 0);
                }
            }
        }
    }
#undef STAGE
#pragma unroll
    for (int qb = 0; qb < 2; ++qb) {
        den[qb] += __shfl_xor(den[qb], 16);
        den[qb] += __shfl_xor(den[qb], 32);
    }
#pragma unroll
    for (int qb = 0; qb < 2; ++qb) {
        float rq[4];
#pragma unroll
        for (int q = 0; q < 4; ++q) rq[q] = 1.0f / __shfl(den[qb], lg*4 + q);
#pragma unroll
        for (int nf = 0; nf < 4; ++nf)
#pragma unroll
            for (int q = 0; q < 4; ++q) {
                int row = i0 + w*32 + qb*16 + lg*4 + q;
                int c = h*64 + nf*16 + lr;
                Out[((size_t)b*2048 + row)*512 + c] = f2bf(acc[qb][nf][q] * rq[q]);
            }
    }
}

// ---------------- output GEMM: merged bf16 @ W + bias -> f32, BM=64, BN=128 (R16-proven) ----------------
__global__ __launch_bounds__(256, 2) void out_gemm(
    const u16* heads_base, const u16* wt, const float* bias0, const float* bias1, float* out) {
    __shared__ u16 Al[64][72];
    __shared__ u16 Bl[128][72];
    int z = blockIdx.z;
    const u16* A = heads_base + (size_t)z * 2097152;
    const u16* Wt = wt + (size_t)(4 + z) * 262144;
    const float* bias = z ? bias1 : bias0;
    float* dst = out + (size_t)z * 2097152;
    int m0 = blockIdx.y * 64, n0 = blockIdx.x * 128;
    int t = threadIdx.x, w = t >> 6, l = t & 63, lg = l >> 4, lr = l & 15;
    f32x4 acc[8] = {};
    for (int k0 = 0; k0 < 512; k0 += 64) {
        __syncthreads();
        for (int it = 0; it < 2; ++it) {           // A: 64x64
            int idx = it * 256 + t;
            int r = idx >> 3, c8 = (idx & 7) << 3;
            *(s16x8*)&Al[r][c8] = *(const s16x8*)(A + (size_t)(m0 + r) * 512 + k0 + c8);
        }
        for (int it = 0; it < 4; ++it) {           // B: 128x64
            int idx = it * 256 + t;
            int r = idx >> 3, c8 = (idx & 7) << 3;
            *(s16x8*)&Bl[r][c8] = *(const s16x8*)(Wt + (size_t)(n0 + r) * 512 + k0 + c8);
        }
        __syncthreads();
        for (int ks = 0; ks < 2; ++ks) {
            s16x8 a = *(const s16x8*)&Al[w*16 + lr][ks*32 + lg*8];
            for (int nf = 0; nf < 8; ++nf) {
                s16x8 b = *(const s16x8*)&Bl[nf*16 + lr][ks*32 + lg*8];
                acc[nf] = __builtin_amdgcn_mfma_f32_16x16x32_bf16(a, b, acc[nf], 0, 0, 0);
            }
        }
    }
    int row = m0 + w*16 + lg*4;
    for (int nf = 0; nf < 8; ++nf) {
        int c = n0 + nf*16 + lr;
        float bv = bias[c];
        for (int r = 0; r < 4; ++r)
            dst[(size_t)(row + r) * 512 + c] = acc[nf][r] + bv;
    }
}

extern "C" void kernel_launch(void* const* d_in, const int* in_sizes, int n_in,
                              void* d_out, int out_size, void* d_ws, size_t ws_size,
                              hipStream_t stream) {
    const float* x      = (const float*)d_in[0];
    const float* ctx    = (const float*)d_in[1];
    const float* w_qk   = (const float*)d_in[2];
    const float* w_cqk  = (const float*)d_in[3];
    const float* w_v    = (const float*)d_in[4];
    const float* w_cv   = (const float*)d_in[5];
    const float* w_out  = (const float*)d_in[6];
    const float* b_out  = (const float*)d_in[7];
    const float* w_cout = (const float*)d_in[8];
    const float* b_cout = (const float*)d_in[9];

    u16* ws   = (u16*)d_ws;
    u16* wt   = ws;                       // 6 * 262144 bf16 weights^T (w_qk^T pre-scaled)
    u16* proj = ws + 1572864;
    u16* qk   = proj;
    u16* cqk  = proj + 2097152;
    u16* vt   = proj + 2 * 2097152;
    u16* cvt  = proj + 3 * 2097152;
    u16* outh = proj + 4 * 2097152;
    u16* ctxh = proj + 5 * 2097152;
    u16* xbf  = outh;                     // cast buffer aliases outh+ctxh (dead until attn writes)
    float* out = (float*)d_out;

    hipLaunchKernelGGL(transpose_w, dim3(8, 8, 6), dim3(256), 0, stream,
                       w_qk, w_cqk, w_v, w_cv, w_out, w_cout, wt);
    hipLaunchKernelGGL(cast_bf16, dim3(4096), dim3(256), 0, stream, x, ctx, xbf);
    hipLaunchKernelGGL(proj_kernel, dim3(8, 32, 4), dim3(256), 0, stream, xbf, wt, proj);
    hipLaunchKernelGGL(attn_single, dim3(16, 16, 2), dim3(256), 0, stream,
                       qk, cqk, vt, cvt, outh, ctxh);
    hipLaunchKernelGGL(out_gemm, dim3(4, 64, 2), dim3(256), 0, stream,
                       outh, wt, b_out, b_cout, out);
}